// Round 5
// baseline (623.636 us; speedup 1.0000x reference)
//
#include <hip/hip_runtime.h>

#define NB 16
#define NC 256
#define NH 64
#define NW 64
#define NK 1024
#define HW (NH * NW)          // 4096
#define NPOS (NB * HW)        // 65536
#define NOUT (NB * NC * HW)   // 16777216
#define NSLOT 256             // loss accumulator slots (atomic spreading)
#define TP 32                 // positions per block (R11: was 64)

__device__ __forceinline__ float sq_rn(float x) { return __fmul_rn(x, x); }

// Exact replica of numpy pairwise_sum for sum(a*a) over n=256 (verified R2/R4).
__device__ __forceinline__ float pairwise_sumsq_256(const float* __restrict__ a,
                                                    int stride) {
    float s_half[2];
#pragma unroll
    for (int h = 0; h < 2; ++h) {
        const float* base = a + (size_t)(h * 128) * stride;
        float r[8];
#pragma unroll
        for (int j = 0; j < 8; ++j) r[j] = sq_rn(base[(size_t)j * stride]);
        for (int i = 8; i < 128; i += 8) {
#pragma unroll
            for (int j = 0; j < 8; ++j)
                r[j] = __fadd_rn(r[j], sq_rn(base[(size_t)(i + j) * stride]));
        }
        s_half[h] = __fadd_rn(
            __fadd_rn(__fadd_rn(r[0], r[1]), __fadd_rn(r[2], r[3])),
            __fadd_rn(__fadd_rn(r[4], r[5]), __fadd_rn(r[6], r[7])));
    }
    return __fadd_rn(s_half[0], s_half[1]);
}

// ---------------------------------------------------------------------------
// Kernel A: cnorm[k] = numpy-fp32 sum(codebook[k]^2)
// ---------------------------------------------------------------------------
__global__ __launch_bounds__(256) void cnorm_kernel(const float* __restrict__ cb,
                                                    float* __restrict__ cnorm) {
    int k = blockIdx.x * 256 + threadIdx.x;
    if (k < NK) {
        cnorm[k] = pairwise_sumsq_256(cb + (size_t)k * NC, 1);
    }
}

// ---------------------------------------------------------------------------
// Kernel A2: pack codebook as cbT2[d/4][k][4] (R10 layout, kept):
//   cbT2[((d>>2)*NK + k)*4 + (d&3)] = cb[k][d]
// A thread's 8 codes x 4 dims = 128 contiguous bytes -> 8 dwordx4 from one
// base + immediate offsets.
// ---------------------------------------------------------------------------
__global__ __launch_bounds__(256) void pack_cb_kernel(const float* __restrict__ cb,
                                                      float* __restrict__ cbT2) {
    const int k = blockIdx.x;    // 0..1023
    const int d = threadIdx.x;   // 0..255
    cbT2[(size_t)((d >> 2) * NK + k) * 4 + (d & 3)] = cb[(size_t)k * NC + d];
}

// ---------------------------------------------------------------------------
// Kernel B (R11): occupancy-for-real. Post-mortems R7-R10: VALU instr count
// varied (VALUBusy 72/62/55%) while memory instr stream + time stayed fixed
// (~470-490us core) -> latency-bound, not issue-bound. OccupancyPercent
// showed R9/R10's 70KB blocks got only 1 block/CU = 2 waves/SIMD — the same
// as R7 — so TLP never actually doubled; 2 phase-locked waves/SIMD stall
// together on each iteration's cb-load latency (~45% idle vs 218us FMA floor).
// R11: 32-pos tiles -> z_lds 32KB, ~34KB/block total -> 4-5 blocks of 256
// thr per CU = 16-20 waves/CU = 4-5 waves/SIMD. Wave owns 256 codes over 4
// passes; per-thread acc[4][8] (4 pos x 8 codes). Cost: 2x cb vmem instrs
// (TCP measured ~23% busy -> headroom).
// Bit-exact: acc = same sequential __fmaf_rn chain over ascending d;
// score = fl(fl(zn+cn)-2*dot); per-thread k ascending across passes
// (stride 64 > cg*8 max); tie-breaks in both reduces; znorm/cnorm paths
// unchanged. Fused gather/loss kept from R10.
// ---------------------------------------------------------------------------
__global__ __launch_bounds__(256, 4) void argmin_kernel(const float* __restrict__ z,
                                                        const float* __restrict__ cb,
                                                        const float* __restrict__ cbT2,
                                                        const float* __restrict__ cnorm,
                                                        float* __restrict__ out,
                                                        float* __restrict__ idx_out,
                                                        double* __restrict__ loss_acc) {
    __shared__ float z_lds[256][TP];      // 32768 B, [d][p] == [c][p]
    __shared__ float znorm_s[TP];         //   128 B
    __shared__ float red_v[4][TP];        //   512 B
    __shared__ int   red_i[4][TP];        //   512 B   -> ~34 KB, 4+ blk/CU

    const int blk = blockIdx.x;           // 0..2047
    const int b = blk >> 7;               // batch (128 tiles per batch)
    const int hw0 = (blk & 127) * TP;     // tile base (32 contiguous positions)
    const int t = threadIdx.x;            // 0..255
    const int lane = t & 63;
    const int wave = t >> 6;              // 0..3
    const int pg = lane & 7;              // position group (4 pos each)
    const int cg = lane >> 3;             // code group (8 codes each)

    const float* zg = z + (size_t)b * (NC * HW) + hw0;

    // ---- stage z d-major: 256x32 floats = 2048 float4 over 256 threads
#pragma unroll
    for (int i = 0; i < 8; ++i) {
        const int d = i * 32 + (t >> 3);
        const int p = (t & 7) * 4;
        const float4 v = *(const float4*)(zg + (size_t)d * HW + p);
        *(float4*)&z_lds[d][p] = v;
    }
    // numpy-exact znorm (same global-strided code path verified in R2/R4)
    if (t < TP) znorm_s[t] = pairwise_sumsq_256(zg + t, HW);
    __syncthreads();                      // the ONLY pre-reduce barrier

    float best[4];
    int bid[4];
#pragma unroll
    for (int i = 0; i < 4; ++i) { best[i] = 3.4e38f; bid[i] = 0; }

#pragma unroll 1
    for (int pass = 0; pass < 4; ++pass) {
        float acc[4][8];
#pragma unroll
        for (int i = 0; i < 4; ++i)
#pragma unroll
            for (int j = 0; j < 8; ++j) acc[i][j] = 0.f;

        // wave owns codes [wave*256, wave*256+256); this pass's 64 of them.
        const int k0 = wave * 256 + pass * 64 + cg * 8;
        const float* cp2 = cbT2 + (size_t)k0 * 4;   // this thread's code base

#pragma unroll 1
        for (int it = 0; it < 64; ++it) { // 4 dims per chunk
            // 8 codes x 4 dims = 128 contiguous bytes: one base + immediates
            float4 cbuf[8];
#pragma unroll
            for (int q = 0; q < 8; ++q)
                cbuf[q] = *(const float4*)(cp2 + (size_t)it * 4096 + q * 4);
#pragma unroll
            for (int dl = 0; dl < 4; ++dl) {
                const int d = it * 4 + dl;
                const float4 za = *(const float4*)&z_lds[d][pg * 4];
                const float zf[4] = {za.x, za.y, za.z, za.w};
#pragma unroll
                for (int i = 0; i < 4; ++i)
#pragma unroll
                    for (int j = 0; j < 8; ++j)
                        acc[i][j] = __fmaf_rn(zf[i],
                                              ((const float*)&cbuf[j])[dl],
                                              acc[i][j]);
            }
        }

        // scores for this pass's 8 codes of this thread (k ascending within
        // thread across passes -> strict < keeps first occurrence)
        const float4 cn0 = *(const float4*)(cnorm + k0);
        const float4 cn1 = *(const float4*)(cnorm + k0 + 4);
        const float cnf[8] = {cn0.x, cn0.y, cn0.z, cn0.w,
                              cn1.x, cn1.y, cn1.z, cn1.w};
        float znl[4];
#pragma unroll
        for (int i = 0; i < 4; ++i) znl[i] = znorm_s[pg * 4 + i];
#pragma unroll
        for (int j = 0; j < 8; ++j) {
            const int k = k0 + j;
#pragma unroll
            for (int i = 0; i < 4; ++i) {
                const float sc = __fsub_rn(__fadd_rn(znl[i], cnf[j]),
                                           __fmul_rn(2.0f, acc[i][j]));
                if (sc < best[i]) { best[i] = sc; bid[i] = k; }
            }
        }
    }

    // ---- reduce across cg (lane stride 8). k-ranges of different cg lanes
    //      INTERLEAVE across passes -> must tie-break on lower index to match
    //      np.argmin first-occurrence (R5 bug).
#pragma unroll
    for (int off = 32; off >= 8; off >>= 1) {
#pragma unroll
        for (int i = 0; i < 4; ++i) {
            const float v = __shfl_down(best[i], off, 64);
            const int d2 = __shfl_down(bid[i], off, 64);
            if (v < best[i] || (v == best[i] && d2 < bid[i])) {
                best[i] = v;
                bid[i] = d2;
            }
        }
    }
    if (cg == 0) {
#pragma unroll
        for (int i = 0; i < 4; ++i) {
            red_v[wave][pg * 4 + i] = best[i];
            red_i[wave][pg * 4 + i] = bid[i];
        }
    }
    __syncthreads();

    // ---- final reduce across 4 waves (disjoint ascending k ranges); publish
    //      final idx in red_i[0][p]
    if (t < TP) {
        float bv = red_v[0][t];
        int bi = red_i[0][t];
#pragma unroll
        for (int w = 1; w < 4; ++w) {
            const float v = red_v[w][t];
            const int i2 = red_i[w][t];
            if (v < bv || (v == bv && i2 < bi)) { bv = v; bi = i2; }
        }
        idx_out[b * HW + hw0 + t] = (float)bi;
        red_i[0][t] = bi;                 // each t touches only column t: safe
    }
    __syncthreads();

    // ---- fused gather + loss: out[b][c][hw0+p] = cb[idx[p]][c];
    //      z_lds[c][p] still holds z for this tile (same bits as global z).
    float* outg = out + (size_t)b * (NC * HW) + hw0;
    float lsum = 0.f;
#pragma unroll 1
    for (int r = 0; r < 8; ++r) {
        const int id = r * 256 + t;       // 0..2047 = [c 0..255][p4 0..7]
        const int c = id >> 3;
        const int p4 = (id & 7) * 4;
        const int i0 = red_i[0][p4];
        const int i1 = red_i[0][p4 + 1];
        const int i2 = red_i[0][p4 + 2];
        const int i3 = red_i[0][p4 + 3];
        float4 o;
        o.x = cb[(size_t)i0 * NC + c];
        o.y = cb[(size_t)i1 * NC + c];
        o.z = cb[(size_t)i2 * NC + c];
        o.w = cb[(size_t)i3 * NC + c];
        *(float4*)(outg + (size_t)c * HW + p4) = o;
        const float4 zv = *(const float4*)&z_lds[c][p4];
        const float d0 = o.x - zv.x;
        const float d1 = o.y - zv.y;
        const float d2 = o.z - zv.z;
        const float d3 = o.w - zv.w;
        lsum += d0 * d0 + d1 * d1 + d2 * d2 + d3 * d3;
    }
#pragma unroll
    for (int off = 32; off > 0; off >>= 1) lsum += __shfl_down(lsum, off, 64);
    if (lane == 0) red_v[wave][0] = lsum;
    __syncthreads();
    if (t == 0) {
        float s = 0.f;
#pragma unroll
        for (int w = 0; w < 4; ++w) s += red_v[w][0];
        atomicAdd(loss_acc + (blk & (NSLOT - 1)), (double)s);
    }
}

// ---------------------------------------------------------------------------
// Kernel D: loss = (1 + beta) * sum / NOUT
// ---------------------------------------------------------------------------
__global__ void finalize_kernel(const double* __restrict__ loss_acc,
                                float* __restrict__ out_loss) {
    if (threadIdx.x == 0) {
        double s = 0.0;
        for (int i = 0; i < NSLOT; ++i) s += loss_acc[i];
        *out_loss = (float)(1.25 * s / (double)NOUT);
    }
}

extern "C" void kernel_launch(void* const* d_in, const int* in_sizes, int n_in,
                              void* d_out, int out_size, void* d_ws, size_t ws_size,
                              hipStream_t stream) {
    const float* z = (const float*)d_in[0];
    const float* cb = (const float*)d_in[1];

    float* out = (float*)d_out;            // [16,256,64,64]
    float* loss_out = out + NOUT;          // scalar
    float* idx_out = out + NOUT + 1;       // [16,1,64,64] as float

    // workspace layout (~1.06 MB):
    //   [0, 2048)        : double loss_acc[NSLOT]
    //   [2048, 6144)     : float  cnorm[1024]
    //   [6144, 1054720)  : float  cbT2[64][1024][4]
    double* loss_acc = (double*)d_ws;
    float* cnorm = (float*)((char*)d_ws + 2048);
    float* cbT2 = (float*)((char*)d_ws + 2048 + 4096);

    hipMemsetAsync(d_ws, 0, 2048, stream);
    cnorm_kernel<<<(NK + 255) / 256, 256, 0, stream>>>(cb, cnorm);
    pack_cb_kernel<<<NK, 256, 0, stream>>>(cb, cbT2);
    argmin_kernel<<<NPOS / TP, 256, 0, stream>>>(z, cb, cbT2, cnorm,
                                                 out, idx_out, loss_acc);
    finalize_kernel<<<1, 64, 0, stream>>>(loss_acc, loss_out);
}

// Round 6
// 543.606 us; speedup vs baseline: 1.1472x; 1.1472x over previous
//
#include <hip/hip_runtime.h>

#define NB 16
#define NC 256
#define NH 64
#define NW 64
#define NK 1024
#define HW (NH * NW)          // 4096
#define NPOS (NB * HW)        // 65536
#define NOUT (NB * NC * HW)   // 16777216
#define NSLOT 256             // loss accumulator slots (atomic spreading)
#define TP 32                 // positions per block

__device__ __forceinline__ float sq_rn(float x) { return __fmul_rn(x, x); }

// Exact replica of numpy pairwise_sum for sum(a*a) over n=256 (verified R2/R4).
__device__ __forceinline__ float pairwise_sumsq_256(const float* __restrict__ a,
                                                    int stride) {
    float s_half[2];
#pragma unroll
    for (int h = 0; h < 2; ++h) {
        const float* base = a + (size_t)(h * 128) * stride;
        float r[8];
#pragma unroll
        for (int j = 0; j < 8; ++j) r[j] = sq_rn(base[(size_t)j * stride]);
        for (int i = 8; i < 128; i += 8) {
#pragma unroll
            for (int j = 0; j < 8; ++j)
                r[j] = __fadd_rn(r[j], sq_rn(base[(size_t)(i + j) * stride]));
        }
        s_half[h] = __fadd_rn(
            __fadd_rn(__fadd_rn(r[0], r[1]), __fadd_rn(r[2], r[3])),
            __fadd_rn(__fadd_rn(r[4], r[5]), __fadd_rn(r[6], r[7])));
    }
    return __fadd_rn(s_half[0], s_half[1]);
}

// ---------------------------------------------------------------------------
// Kernel A: cnorm[k] = numpy-fp32 sum(codebook[k]^2)
// ---------------------------------------------------------------------------
__global__ __launch_bounds__(256) void cnorm_kernel(const float* __restrict__ cb,
                                                    float* __restrict__ cnorm) {
    int k = blockIdx.x * 256 + threadIdx.x;
    if (k < NK) {
        cnorm[k] = pairwise_sumsq_256(cb + (size_t)k * NC, 1);
    }
}

// ---------------------------------------------------------------------------
// Kernel A2 (R12): q-major packed codebook.
// Blocks of 128 codes; within a block, code k sits at slot (k&7)*16+((k>>3)&15).
// Per 4-dim chunk `it`: cbT3[it][kblk][slot][4].
// Effect: in argmin, load-instruction q across the 16 cg-lanes reads 16
// CONTIGUOUS float4 (256 B, 4 cachelines) instead of 8 scattered lines at
// stride 128 B — 4x fewer L1 line-lookups, fully coalesced.
// ---------------------------------------------------------------------------
__global__ __launch_bounds__(256) void pack_cb_kernel(const float* __restrict__ cb,
                                                      float* __restrict__ cbT3) {
    const int k = blockIdx.x;    // 0..1023
    const int d = threadIdx.x;   // 0..255
    const int it = d >> 2, dl = d & 3;
    const int kb = k >> 7;               // 128-code block
    const int q = k & 7;                 // code-within-thread
    const int cgi = (k >> 3) & 15;       // cg lane
    cbT3[(size_t)(((it * 8 + kb) * 128) + q * 16 + cgi) * 4 + dl] =
        cb[(size_t)k * NC + d];
}

// ---------------------------------------------------------------------------
// Kernel B (R12): coalesced cb stream + high FMA/load ratio + real occupancy.
// R7-R11 post-mortems: time tracks the cb vmem request stream, not VALU count
// (R10: -7% VALUBusy, flat), not occupancy (R11: occ 23->40%, WORSE because
// vmem/FMA doubled). Old layout: each cb load instr = 8 lanes at stride 128B
// = 8 scattered lines, each line requested by 4 instrs (64 lookups / 16
// unique lines per wave-it) -> L1/TA pipe bound; 1MB cb never fits 32KB L1.
// R12: (a) cbT3 q-major packing -> every cb instr contiguous 256B/4 lines;
// (b) TP=32 with P=8 pos x C=8 codes per thread (pg=lane>>4, cg=lane&15):
// keeps R10's 256 FMA per 8 loads; LDS 34KB -> 4 blocks/CU ~ 16 waves/CU;
// (c) launch_bounds(256,2): no forced-spill (R8 lesson), compiler lands
// ~110-150 VGPR.
// Bit-exact: same sequential __fmaf_rn chain over ascending d; score =
// fl(fl(zn+cn)-2*dot); per-thread k strictly ascending across passes
// (stride 128 > cg*8+7); tie-breaks in both reduces (cross-cg k-ranges
// interleave across passes). Fused gather/loss kept.
// ---------------------------------------------------------------------------
__global__ __launch_bounds__(256, 2) void argmin_kernel(const float* __restrict__ z,
                                                        const float* __restrict__ cb,
                                                        const float* __restrict__ cbT3,
                                                        const float* __restrict__ cnorm,
                                                        float* __restrict__ out,
                                                        float* __restrict__ idx_out,
                                                        double* __restrict__ loss_acc) {
    __shared__ float z_lds[256][TP];      // 32768 B, [d][p] == [c][p]
    __shared__ float znorm_s[TP];         //   128 B
    __shared__ float red_v[4][TP];        //   512 B
    __shared__ int   red_i[4][TP];        //   512 B   -> ~34 KB, 4 blk/CU

    const int blk = blockIdx.x;           // 0..2047
    const int b = blk >> 7;               // batch (128 tiles per batch)
    const int hw0 = (blk & 127) * TP;     // tile base (32 contiguous positions)
    const int t = threadIdx.x;            // 0..255
    const int lane = t & 63;
    const int wave = t >> 6;              // 0..3
    const int pg = lane >> 4;             // position group: 4 groups x 8 pos
    const int cg = lane & 15;             // code group: 16 groups x 8 codes

    const float* zg = z + (size_t)b * (NC * HW) + hw0;

    // ---- stage z d-major: 256x32 floats = 2048 float4 over 256 threads
#pragma unroll
    for (int i = 0; i < 8; ++i) {
        const int d = i * 32 + (t >> 3);
        const int p = (t & 7) * 4;
        const float4 v = *(const float4*)(zg + (size_t)d * HW + p);
        *(float4*)&z_lds[d][p] = v;
    }
    // numpy-exact znorm (same global-strided code path verified in R2/R4)
    if (t < TP) znorm_s[t] = pairwise_sumsq_256(zg + t, HW);
    __syncthreads();                      // the ONLY pre-reduce barrier

    float best[8];
    int bid[8];
#pragma unroll
    for (int i = 0; i < 8; ++i) { best[i] = 3.4e38f; bid[i] = 0; }

#pragma unroll 1
    for (int pass = 0; pass < 2; ++pass) {
        float acc[8][8];
#pragma unroll
        for (int i = 0; i < 8; ++i)
#pragma unroll
            for (int j = 0; j < 8; ++j) acc[i][j] = 0.f;

        // wave owns codes [wave*256, +256); this pass: 16 cgs x 8 codes = 128.
        const int k0 = wave * 256 + pass * 128 + cg * 8;
        // packed base: block (wave*2+pass), slot column cg
        const float* cp3 = cbT3 + (size_t)((wave * 2 + pass) * 512 + cg * 4);

#pragma unroll 1
        for (int it = 0; it < 64; ++it) { // 4 dims per chunk
            // 8 loads; instr q: 16 cg-lanes contiguous 256 B (coalesced)
            float4 cbuf[8];
#pragma unroll
            for (int q = 0; q < 8; ++q)
                cbuf[q] = *(const float4*)(cp3 + (size_t)it * 4096 + q * 64);
#pragma unroll
            for (int dl = 0; dl < 4; ++dl) {
                const int d = it * 4 + dl;
                const float4 za = *(const float4*)&z_lds[d][pg * 8];
                const float4 zb = *(const float4*)&z_lds[d][pg * 8 + 4];
                const float zf[8] = {za.x, za.y, za.z, za.w,
                                     zb.x, zb.y, zb.z, zb.w};
#pragma unroll
                for (int i = 0; i < 8; ++i)
#pragma unroll
                    for (int j = 0; j < 8; ++j)
                        acc[i][j] = __fmaf_rn(zf[i],
                                              ((const float*)&cbuf[j])[dl],
                                              acc[i][j]);
            }
        }

        // scores for this pass's 8 codes (k ascending within thread across
        // passes -> strict < keeps first occurrence)
        const float4 cn0 = *(const float4*)(cnorm + k0);
        const float4 cn1 = *(const float4*)(cnorm + k0 + 4);
        const float cnf[8] = {cn0.x, cn0.y, cn0.z, cn0.w,
                              cn1.x, cn1.y, cn1.z, cn1.w};
        float znl[8];
#pragma unroll
        for (int i = 0; i < 8; ++i) znl[i] = znorm_s[pg * 8 + i];
#pragma unroll
        for (int j = 0; j < 8; ++j) {
            const int k = k0 + j;
#pragma unroll
            for (int i = 0; i < 8; ++i) {
                const float sc = __fsub_rn(__fadd_rn(znl[i], cnf[j]),
                                           __fmul_rn(2.0f, acc[i][j]));
                if (sc < best[i]) { best[i] = sc; bid[i] = k; }
            }
        }
    }

    // ---- reduce across the 16 cg-lanes of each pg group (offsets 8,4,2,1).
    //      Lanes whose shuffle source crosses the 16-lane group get garbage,
    //      but those lanes provably never feed lane cg==0's final value.
    //      k-ranges of different cgs INTERLEAVE across passes -> tie-break
    //      on lower index to match np.argmin first-occurrence.
#pragma unroll
    for (int off = 8; off >= 1; off >>= 1) {
#pragma unroll
        for (int i = 0; i < 8; ++i) {
            const float v = __shfl_down(best[i], off, 64);
            const int d2 = __shfl_down(bid[i], off, 64);
            if (v < best[i] || (v == best[i] && d2 < bid[i])) {
                best[i] = v;
                bid[i] = d2;
            }
        }
    }
    if (cg == 0) {
#pragma unroll
        for (int i = 0; i < 8; ++i) {
            red_v[wave][pg * 8 + i] = best[i];
            red_i[wave][pg * 8 + i] = bid[i];
        }
    }
    __syncthreads();

    // ---- final reduce across 4 waves (disjoint ascending k ranges); publish
    //      final idx in red_i[0][p]
    if (t < TP) {
        float bv = red_v[0][t];
        int bi = red_i[0][t];
#pragma unroll
        for (int w = 1; w < 4; ++w) {
            const float v = red_v[w][t];
            const int i2 = red_i[w][t];
            if (v < bv || (v == bv && i2 < bi)) { bv = v; bi = i2; }
        }
        idx_out[b * HW + hw0 + t] = (float)bi;
        red_i[0][t] = bi;                 // each t touches only column t: safe
    }
    __syncthreads();

    // ---- fused gather + loss: out[b][c][hw0+p] = cb[idx[p]][c];
    //      z_lds[c][p] still holds z for this tile (same bits as global z).
    float* outg = out + (size_t)b * (NC * HW) + hw0;
    float lsum = 0.f;
#pragma unroll 1
    for (int r = 0; r < 8; ++r) {
        const int id = r * 256 + t;       // 0..2047 = [c 0..255][p4 0..7]
        const int c = id >> 3;
        const int p4 = (id & 7) * 4;
        const int i0 = red_i[0][p4];
        const int i1 = red_i[0][p4 + 1];
        const int i2 = red_i[0][p4 + 2];
        const int i3 = red_i[0][p4 + 3];
        float4 o;
        o.x = cb[(size_t)i0 * NC + c];
        o.y = cb[(size_t)i1 * NC + c];
        o.z = cb[(size_t)i2 * NC + c];
        o.w = cb[(size_t)i3 * NC + c];
        *(float4*)(outg + (size_t)c * HW + p4) = o;
        const float4 zv = *(const float4*)&z_lds[c][p4];
        const float d0 = o.x - zv.x;
        const float d1 = o.y - zv.y;
        const float d2 = o.z - zv.z;
        const float d3 = o.w - zv.w;
        lsum += d0 * d0 + d1 * d1 + d2 * d2 + d3 * d3;
    }
#pragma unroll
    for (int off = 32; off > 0; off >>= 1) lsum += __shfl_down(lsum, off, 64);
    if (lane == 0) red_v[wave][0] = lsum;
    __syncthreads();
    if (t == 0) {
        float s = 0.f;
#pragma unroll
        for (int w = 0; w < 4; ++w) s += red_v[w][0];
        atomicAdd(loss_acc + (blk & (NSLOT - 1)), (double)s);
    }
}

// ---------------------------------------------------------------------------
// Kernel D: loss = (1 + beta) * sum / NOUT
// ---------------------------------------------------------------------------
__global__ void finalize_kernel(const double* __restrict__ loss_acc,
                                float* __restrict__ out_loss) {
    if (threadIdx.x == 0) {
        double s = 0.0;
        for (int i = 0; i < NSLOT; ++i) s += loss_acc[i];
        *out_loss = (float)(1.25 * s / (double)NOUT);
    }
}

extern "C" void kernel_launch(void* const* d_in, const int* in_sizes, int n_in,
                              void* d_out, int out_size, void* d_ws, size_t ws_size,
                              hipStream_t stream) {
    const float* z = (const float*)d_in[0];
    const float* cb = (const float*)d_in[1];

    float* out = (float*)d_out;            // [16,256,64,64]
    float* loss_out = out + NOUT;          // scalar
    float* idx_out = out + NOUT + 1;       // [16,1,64,64] as float

    // workspace layout (~1.06 MB):
    //   [0, 2048)        : double loss_acc[NSLOT]
    //   [2048, 6144)     : float  cnorm[1024]
    //   [6144, 1054720)  : float  cbT3[64][8][128][4]
    double* loss_acc = (double*)d_ws;
    float* cnorm = (float*)((char*)d_ws + 2048);
    float* cbT3 = (float*)((char*)d_ws + 2048 + 4096);

    hipMemsetAsync(d_ws, 0, 2048, stream);
    cnorm_kernel<<<(NK + 255) / 256, 256, 0, stream>>>(cb, cnorm);
    pack_cb_kernel<<<NK, 256, 0, stream>>>(cb, cbT3);
    argmin_kernel<<<NPOS / TP, 256, 0, stream>>>(z, cb, cbT3, cnorm,
                                                 out, idx_out, loss_acc);
    finalize_kernel<<<1, 64, 0, stream>>>(loss_acc, loss_out);
}